// Round 12
// baseline (131.500 us; speedup 1.0000x reference)
//
#include <hip/hip_runtime.h>
#include <hip/hip_bf16.h>

#define B_ 4
#define C_IN_ 384
#define C_OUT_ 768
#define N_ 8192
#define K_ 16
#define FANIN_ 192     // 2*C_IN/GROUPS
#define NT 16          // n-columns per block (24.8KB LDS -> 4 blocks/CU = 32 waves)
#define PADC (2*C_IN_ + 8)   // 776 shorts: pad to break 1552B-stride bank conflicts

typedef float f32x4 __attribute__((ext_vector_type(4)));
typedef short bf16x8 __attribute__((ext_vector_type(8)));

__device__ __forceinline__ unsigned short f2b(float f) {
  union { float f; unsigned u; } v; v.f = f;
  unsigned r = v.u + 0x7FFFu + ((v.u >> 16) & 1u);  // RNE
  return (unsigned short)(r >> 16);
}

// ---- kernel 1: W fp32 -> bf16 (original fanin order: interleaved (x,rel)) ----
__global__ __launch_bounds__(256) void wconv_kernel(const float* __restrict__ W,
                                                    unsigned short* __restrict__ Wb) {
  int i = blockIdx.x * 256 + threadIdx.x;
  if (i < C_OUT_ * FANIN_) Wb[i] = f2b(W[i]);
}

// ---- kernel 2: transpose x [B][C][N] f32 -> xt [B][N][C] bf16 + xq int8 (x16) ----
__global__ __launch_bounds__(256) void transpose_kernel(const float* __restrict__ x,
                                                        unsigned short* __restrict__ xt,
                                                        char* __restrict__ xq) {
  __shared__ float tile[32][65];
  int n0 = blockIdx.x * 32;
  int c0 = blockIdx.y * 64;
  int b  = blockIdx.z;
  int tx = threadIdx.x & 31;
  int ty = threadIdx.x >> 5;
  const float* xp = x + (size_t)b * C_IN_ * N_;
  #pragma unroll
  for (int r = 0; r < 8; ++r) {
    int c = c0 + r * 8 + ty;
    tile[tx][r * 8 + ty] = xp[(size_t)c * N_ + n0 + tx];   // coalesced along n
  }
  __syncthreads();
  // bf16 out (exact self values)
  unsigned short* outp = xt + ((size_t)b * N_ + n0) * C_IN_ + c0;
  int cp = threadIdx.x & 31;
  int ny = threadIdx.x >> 5;
  #pragma unroll
  for (int p = 0; p < 4; ++p) {
    int nl = ny + p * 8;
    unsigned pk = (unsigned)f2b(tile[nl][cp * 2]) |
                  ((unsigned)f2b(tile[nl][cp * 2 + 1]) << 16);
    *(unsigned*)(outp + (size_t)nl * C_IN_ + cp * 2) = pk;
  }
  // int8 out (scale 16, RN, clamp +-127), linear channel order
  char* qout = xq + ((size_t)b * N_ + n0) * C_IN_ + c0;
  #pragma unroll
  for (int u = 0; u < 2; ++u) {
    int uu = u * 256 + threadIdx.x;
    int nl = uu >> 4;            // 0..31
    int c4 = uu & 15;            // dword within the 64-channel slab
    unsigned pk = 0;
    #pragma unroll
    for (int e = 0; e < 4; ++e) {
      int q = __float2int_rn(tile[nl][c4 * 4 + e] * 16.0f);
      q = q > 127 ? 127 : (q < -127 ? -127 : q);
      pk |= ((unsigned)(q & 0xff)) << (8 * e);
    }
    *(unsigned*)(qout + (size_t)nl * C_IN_ + c4 * 4) = pk;
  }
}

// ---- kernel 3: int8 gather+max (R7 structure, NT=16 for 32 waves/CU) -> MFMA ----
__global__ __launch_bounds__(512) void mrconv_kernel(
    const unsigned short* __restrict__ xt,   // [B][N][384] bf16 (self, exact)
    const char* __restrict__ xq,             // [B][N][384] int8 (gather, x16)
    const int* __restrict__ eidx,            // [2][B][N][K]
    const unsigned short* __restrict__ Wb,   // [C_OUT][FANIN] bf16
    const float* __restrict__ bias,          // [C_OUT]
    float* __restrict__ out)                 // [B][C_OUT][N]
{
  __shared__ unsigned short m_lds[NT][PADC];  // merged: interleaved (x_c, rel_c)
  int tile = blockIdx.x;
  int b    = blockIdx.y;
  int n0   = tile * NT;
  int tid  = threadIdx.x;
  int wv   = tid >> 6;
  int lane = tid & 63;

  const unsigned short* xtb = xt + (size_t)b * N_ * C_IN_;
  const char* xqb = xq + (size_t)b * N_ * C_IN_;
  const int* e0p = eidx + ((size_t)b * N_) * K_;          // edge_index[0][b] -> j
  const int* e1p = eidx + ((size_t)(B_ + b) * N_) * K_;   // edge_index[1][b] -> i

  // -------- phase 1: gather + max-relative (48 lanes x 8 ch, 2 cols/wave) ----
  for (int s = 0; s < 2; ++s) {
    int nl = wv * 2 + s;                                   // 8 waves x 2 cols = 16
    int nb = __builtin_amdgcn_readfirstlane(n0 + nl);
    const int* e0 = e0p + (size_t)nb * K_;
    const int* e1 = e1p + (size_t)nb * K_;
    if (lane < 48) {
      uint4 xv = *(const uint4*)(xtb + (size_t)nb * C_IN_ + lane * 8);  // self bf16
      const char* xqc = xqb + lane * 8;                    // int8 channel base

      int mx[8];
      #pragma unroll
      for (int c = 0; c < 8; ++c) mx[c] = -512;

      #pragma unroll 4
      for (int k = 0; k < K_; ++k) {
        int j = __builtin_amdgcn_readfirstlane(e0[k]);
        int i = __builtin_amdgcn_readfirstlane(e1[k]);
        uint2 vj = *(const uint2*)(xqc + (size_t)j * C_IN_);   // 8 int8 ch
        uint2 vi = *(const uint2*)(xqc + (size_t)i * C_IN_);
        unsigned aj[2] = {vj.x, vj.y};
        unsigned ai[2] = {vi.x, vi.y};
        #pragma unroll
        for (int d = 0; d < 2; ++d)
          #pragma unroll
          for (int e = 0; e < 4; ++e) {
            int sj = (int)(signed char)((aj[d] >> (8 * e)) & 0xffu);
            int si = (int)(signed char)((ai[d] >> (8 * e)) & 0xffu);
            int df = sj - si;
            mx[4 * d + e] = df > mx[4 * d + e] ? df : mx[4 * d + e];
          }
      }

      // pack interleaved (x_c, rel_c): dword c = x_c | rel_c<<16
      unsigned ux[4] = {xv.x, xv.y, xv.z, xv.w};
      unsigned od[8];
      #pragma unroll
      for (int c = 0; c < 8; ++c) {
        unsigned xs = (ux[c >> 1] >> ((c & 1) * 16)) & 0xffffu;
        od[c] = xs | ((unsigned)f2b((float)mx[c] * 0.0625f) << 16);
      }
      uint4 o0; o0.x = od[0]; o0.y = od[1]; o0.z = od[2]; o0.w = od[3];
      uint4 o1; o1.x = od[4]; o1.y = od[5]; o1.z = od[6]; o1.w = od[7];
      *(uint4*)&m_lds[nl][lane * 16] = o0;
      *(uint4*)&m_lds[nl][lane * 16 + 8] = o1;
    }
  }
  __syncthreads();

  // -------- phase 2: grouped GEMM via MFMA --------
  // wave wv -> group g = wv>>1, cout half = wv&1: owns 96 rows x 16 cols
  int g    = wv >> 1;
  int half = wv & 1;
  int rb   = g * 192 + half * 96;    // cout base
  int l15  = lane & 15;
  int lhi  = lane >> 4;

  f32x4 acc[6];
  #pragma unroll
  for (int rt = 0; rt < 6; ++rt) acc[rt] = (f32x4){0.f, 0.f, 0.f, 0.f};

  #pragma unroll
  for (int ks = 0; ks < 6; ++ks) {           // K = 192 = 6 x 32
    int k0 = ks * 32 + lhi * 8;
    bf16x8 bfrag = *(const bf16x8*)&m_lds[l15][g * FANIN_ + k0];   // B[k][n]
    #pragma unroll
    for (int rt = 0; rt < 6; ++rt) {
      int co = rb + rt * 16 + l15;
      bf16x8 afrag = *(const bf16x8*)(Wb + (size_t)co * FANIN_ + k0);  // A[m][k]
      acc[rt] = __builtin_amdgcn_mfma_f32_16x16x32_bf16(afrag, bfrag,
                                                        acc[rt], 0, 0, 0);
    }
  }

  // -------- epilogue: bias + ReLU, store --------
  float* outb = out + (size_t)b * C_OUT_ * N_;
  int n = n0 + l15;                          // D col = lane&15
  #pragma unroll
  for (int rt = 0; rt < 6; ++rt) {
    int co_b = rb + rt * 16 + lhi * 4;       // D row = (lane>>4)*4 + reg (m89-verified)
    #pragma unroll
    for (int r = 0; r < 4; ++r) {
      int co = co_b + r;
      float v = acc[rt][r] + bias[co];
      outb[(size_t)co * N_ + n] = v > 0.f ? v : 0.f;
    }
  }
}

extern "C" void kernel_launch(void* const* d_in, const int* in_sizes, int n_in,
                              void* d_out, int out_size, void* d_ws, size_t ws_size,
                              hipStream_t stream) {
  const float* x    = (const float*)d_in[0];
  const int*   eidx = (const int*)d_in[1];
  const float* W    = (const float*)d_in[2];
  const float* bias = (const float*)d_in[3];
  float* out = (float*)d_out;

  unsigned short* xt = (unsigned short*)d_ws;                 // 25.2 MB bf16
  unsigned short* Wb = xt + (size_t)B_ * N_ * C_IN_;          // 0.3 MB bf16
  char*           xq = (char*)(Wb + (size_t)C_OUT_ * FANIN_); // 12.6 MB int8

  wconv_kernel<<<(C_OUT_ * FANIN_ + 255) / 256, 256, 0, stream>>>(W, Wb);

  dim3 tg(N_ / 32, C_IN_ / 64, B_);
  transpose_kernel<<<tg, 256, 0, stream>>>(x, xt, xq);

  dim3 mg(N_ / NT, B_);
  mrconv_kernel<<<mg, 512, 0, stream>>>(xt, xq, eidx, Wb, bias, out);
}

// Round 14
// 94.975 us; speedup vs baseline: 1.3846x; 1.3846x over previous
//
#include <hip/hip_runtime.h>
#include <hip/hip_bf16.h>

#define B_ 4
#define C_IN_ 384
#define C_OUT_ 768
#define N_ 8192
#define K_ 16
#define FANIN_ 192     // 2*C_IN/GROUPS
#define NT 32          // n-columns per block; 8 waves x 4 cols
#define PADC (2*C_IN_ + 8)   // 776 shorts: merged row stride (split [x96|rel96] x4g)

typedef float f32x4 __attribute__((ext_vector_type(4)));
typedef short bf16x8 __attribute__((ext_vector_type(8)));
typedef short s16x2 __attribute__((ext_vector_type(2)));

__device__ __forceinline__ unsigned short f2b(float f) {
  union { float f; unsigned u; } v; v.f = f;
  unsigned r = v.u + 0x7FFFu + ((v.u >> 16) & 1u);  // RNE
  return (unsigned short)(r >> 16);
}

// ---- kernel 1: W fp32 -> bf16, k-reordered to [x96|rel96] per group ----
// merged k' in [0,192): k'<96 -> orig fanin 2k' (x), else 2(k'-96)+1 (rel)
__global__ __launch_bounds__(256) void wconv_kernel(const float* __restrict__ W,
                                                    unsigned short* __restrict__ Wb) {
  int i = blockIdx.x * 256 + threadIdx.x;
  if (i < C_OUT_ * FANIN_) {
    int kp = i % FANIN_;
    int o  = i / FANIN_;
    int f  = (kp < 96) ? (2 * kp) : (2 * (kp - 96) + 1);
    Wb[i] = f2b(W[(size_t)o * FANIN_ + f]);
  }
}

// ---- kernel 2: transpose x -> xt [B][N][C] bf16 + xq BIASED uint8 (x16+128) ----
__global__ __launch_bounds__(256) void transpose_kernel(const float* __restrict__ x,
                                                        unsigned short* __restrict__ xt,
                                                        unsigned char* __restrict__ xq) {
  __shared__ float tile[32][65];
  int n0 = blockIdx.x * 32;
  int c0 = blockIdx.y * 64;
  int b  = blockIdx.z;
  int tx = threadIdx.x & 31;
  int ty = threadIdx.x >> 5;
  const float* xp = x + (size_t)b * C_IN_ * N_;
  #pragma unroll
  for (int r = 0; r < 8; ++r) {
    int c = c0 + r * 8 + ty;
    tile[tx][r * 8 + ty] = xp[(size_t)c * N_ + n0 + tx];   // coalesced along n
  }
  __syncthreads();
  unsigned short* outp = xt + ((size_t)b * N_ + n0) * C_IN_ + c0;
  int cp = threadIdx.x & 31;
  int ny = threadIdx.x >> 5;
  #pragma unroll
  for (int p = 0; p < 4; ++p) {
    int nl = ny + p * 8;
    unsigned pk = (unsigned)f2b(tile[nl][cp * 2]) |
                  ((unsigned)f2b(tile[nl][cp * 2 + 1]) << 16);
    *(unsigned*)(outp + (size_t)nl * C_IN_ + cp * 2) = pk;
  }
  // biased uint8: q = clamp(rn(x*16)+128, 0, 255); diffs exact in 16-bit SWAR
  unsigned char* qout = xq + ((size_t)b * N_ + n0) * C_IN_ + c0;
  #pragma unroll
  for (int u = 0; u < 2; ++u) {
    int uu = u * 256 + threadIdx.x;
    int nl = uu >> 4;
    int c4 = uu & 15;
    unsigned pk = 0;
    #pragma unroll
    for (int e = 0; e < 4; ++e) {
      int q = __float2int_rn(tile[nl][c4 * 4 + e] * 16.0f) + 128;
      q = q < 0 ? 0 : (q > 255 ? 255 : q);
      pk |= ((unsigned)q) << (8 * e);
    }
    *(unsigned*)(qout + (size_t)nl * C_IN_ + c4 * 4) = pk;
  }
}

// ---- kernel 3: 2-rows-per-load gather (16 VMEM/col) + SWAR max -> MFMA ----
__global__ __launch_bounds__(512) void mrconv_kernel(
    const unsigned short* __restrict__ xt,   // [B][N][384] bf16 (self, exact)
    const unsigned char* __restrict__ xq,    // [B][N][384] biased uint8
    const int* __restrict__ eidx,            // [2][B][N][K]
    const unsigned short* __restrict__ Wb,   // [C_OUT][192] bf16, k-reordered
    const float* __restrict__ bias,          // [C_OUT]
    float* __restrict__ out)                 // [B][C_OUT][N]
{
  __shared__ unsigned short m_lds[NT][PADC];  // merged [x96|rel96] x 4 groups
  int tile = blockIdx.x;
  int b    = blockIdx.y;
  int n0   = tile * NT;
  int tid  = threadIdx.x;
  int wv   = tid >> 6;         // 8 waves
  int lane = tid & 63;
  int h    = lane >> 5;        // k-parity handled by this lane (0=even,1=odd)
  int c    = lane & 31;        // 12-byte channel chunk within row

  const unsigned short* xtb = xt + (size_t)b * N_ * C_IN_;
  const unsigned char*  xqb = xq + (size_t)b * N_ * C_IN_;
  const int* e0p = eidx + ((size_t)b * N_) * K_;          // -> j
  const int* e1p = eidx + ((size_t)(B_ + b) * N_) * K_;   // -> i

  const unsigned char* xqc = xqb + c * 12;   // per-lane channel base

  for (int s = 0; s < 4; ++s) {
    int nl = wv * 4 + s;                     // 8 waves x 4 cols = 32
    int nb = __builtin_amdgcn_readfirstlane(n0 + nl);
    const int* e0 = e0p + (size_t)nb * K_;
    const int* e1 = e1p + (size_t)nb * K_;
    int sj[16], si[16];
    #pragma unroll
    for (int k = 0; k < 16; ++k) {
      sj[k] = __builtin_amdgcn_readfirstlane(e0[k]);
      si[k] = __builtin_amdgcn_readfirstlane(e1[k]);
    }
    uint4 xv;
    if (lane < 48) xv = *(const uint4*)(xtb + (size_t)nb * C_IN_ + lane * 8);

    s16x2 me[3], mo[3];                      // packed maxes: even/odd channels
    #pragma unroll
    for (int d = 0; d < 3; ++d) {
      me[d] = (s16x2){-512, -512};
      mo[d] = (s16x2){-512, -512};
    }

    #pragma unroll
    for (int t = 0; t < 8; ++t) {            // k = 2t + h: 2 rows per instruction
      int jrow = h ? sj[2 * t + 1] : sj[2 * t];   // v_cndmask from SGPRs
      int irow = h ? si[2 * t + 1] : si[2 * t];
      uint3 vj = *(const uint3*)(xqc + (size_t)jrow * C_IN_);   // 12 ch, dwordx3
      uint3 vi = *(const uint3*)(xqc + (size_t)irow * C_IN_);
      unsigned uj[3] = {vj.x, vj.y, vj.z};
      unsigned ui[3] = {vi.x, vi.y, vi.z};
      #pragma unroll
      for (int d = 0; d < 3; ++d) {
        // SWAR: biased bytes -> u16 lanes; diff exact; packed i16 max
        s16x2 je = __builtin_bit_cast(s16x2, uj[d] & 0x00FF00FFu);
        s16x2 jo = __builtin_bit_cast(s16x2, (uj[d] >> 8) & 0x00FF00FFu);
        s16x2 ie = __builtin_bit_cast(s16x2, ui[d] & 0x00FF00FFu);
        s16x2 io = __builtin_bit_cast(s16x2, (ui[d] >> 8) & 0x00FF00FFu);
        s16x2 de = je - ie;
        s16x2 dd = jo - io;
        me[d] = __builtin_elementwise_max(me[d], de);
        mo[d] = __builtin_elementwise_max(mo[d], dd);
      }
    }
    // merge k-parity halves (lane ^ 32 has same channels, other parity)
    #pragma unroll
    for (int d = 0; d < 3; ++d) {
      s16x2 oe = __builtin_bit_cast(s16x2, __shfl_xor(__builtin_bit_cast(int, me[d]), 32));
      me[d] = __builtin_elementwise_max(me[d], oe);
      s16x2 oo = __builtin_bit_cast(s16x2, __shfl_xor(__builtin_bit_cast(int, mo[d]), 32));
      mo[d] = __builtin_elementwise_max(mo[d], oo);
    }

    int col = nl;
    if (h == 0) {                            // lanes 0..31: rel channels [12c,12c+12)
      int gch = c * 12;                      // chunks align to group bounds (96/12=8)
      int g   = gch / 96;
      int pos = g * 192 + 96 + (gch - g * 96);
      unsigned short* dst = &m_lds[col][pos];
      unsigned w[6];
      #pragma unroll
      for (int d = 0; d < 3; ++d) {
        // ch 4d+0=me.x, 4d+1=mo.x, 4d+2=me.y, 4d+3=mo.y
        unsigned w0 = f2b((float)me[d][0] * 0.0625f);
        unsigned w1 = f2b((float)mo[d][0] * 0.0625f);
        unsigned w2 = f2b((float)me[d][1] * 0.0625f);
        unsigned w3 = f2b((float)mo[d][1] * 0.0625f);
        w[2 * d]     = w0 | (w1 << 16);
        w[2 * d + 1] = w2 | (w3 << 16);
      }
      *(uint2*)(dst)     = (uint2){w[0], w[1]};
      *(uint2*)(dst + 4) = (uint2){w[2], w[3]};
      *(uint2*)(dst + 8) = (uint2){w[4], w[5]};
    }
    if (lane < 48) {                         // x channels [8*lane, 8*lane+8)
      int gch = lane * 8;
      int g   = gch / 96;
      int pos = g * 192 + (gch - g * 96);
      *(uint4*)&m_lds[col][pos] = xv;
    }
  }
  __syncthreads();

  // -------- phase 2: grouped GEMM via MFMA (R7-verified shape) --------
  // wave wv -> group g = wv>>1, cout half = wv&1: owns 96 rows x 32 cols
  int g2   = wv >> 1;
  int half = wv & 1;
  int rb   = g2 * 192 + half * 96;   // cout base
  int l15  = lane & 15;
  int lhi  = lane >> 4;

  f32x4 acc[6][2];
  #pragma unroll
  for (int rt = 0; rt < 6; ++rt)
    #pragma unroll
    for (int ct = 0; ct < 2; ++ct)
      acc[rt][ct] = (f32x4){0.f, 0.f, 0.f, 0.f};

  #pragma unroll
  for (int ks = 0; ks < 6; ++ks) {           // K' = 192 = 6 x 32 (reordered k)
    int k0 = ks * 32 + lhi * 8;
    bf16x8 bfrag[2];
    #pragma unroll
    for (int ct = 0; ct < 2; ++ct) {
      int n = ct * 16 + l15;
      bfrag[ct] = *(const bf16x8*)&m_lds[n][g2 * 192 + k0];
    }
    #pragma unroll
    for (int rt = 0; rt < 6; ++rt) {
      int co = rb + rt * 16 + l15;
      bf16x8 afrag = *(const bf16x8*)(Wb + (size_t)co * FANIN_ + k0);
      #pragma unroll
      for (int ct = 0; ct < 2; ++ct)
        acc[rt][ct] = __builtin_amdgcn_mfma_f32_16x16x32_bf16(afrag, bfrag[ct],
                                                              acc[rt][ct], 0, 0, 0);
    }
  }

  // -------- epilogue: bias + ReLU, store --------
  float* outb = out + (size_t)b * C_OUT_ * N_;
  #pragma unroll
  for (int rt = 0; rt < 6; ++rt) {
    int co_b = rb + rt * 16 + lhi * 4;       // D row = (lane>>4)*4 + reg (m89-verified)
    #pragma unroll
    for (int ct = 0; ct < 2; ++ct) {
      int n = n0 + ct * 16 + l15;            // D col = lane&15
      #pragma unroll
      for (int r = 0; r < 4; ++r) {
        int co = co_b + r;
        float v = acc[rt][ct][r] + bias[co];
        outb[(size_t)co * N_ + n] = v > 0.f ? v : 0.f;
      }
    }
  }
}

extern "C" void kernel_launch(void* const* d_in, const int* in_sizes, int n_in,
                              void* d_out, int out_size, void* d_ws, size_t ws_size,
                              hipStream_t stream) {
  const float* x    = (const float*)d_in[0];
  const int*   eidx = (const int*)d_in[1];
  const float* W    = (const float*)d_in[2];
  const float* bias = (const float*)d_in[3];
  float* out = (float*)d_out;

  unsigned short* xt = (unsigned short*)d_ws;                 // 25.2 MB bf16
  unsigned short* Wb = xt + (size_t)B_ * N_ * C_IN_;          // 0.3 MB bf16
  unsigned char*  xq = (unsigned char*)(Wb + (size_t)C_OUT_ * FANIN_); // 12.6 MB u8

  wconv_kernel<<<(C_OUT_ * FANIN_ + 255) / 256, 256, 0, stream>>>(W, Wb);

  dim3 tg(N_ / 32, C_IN_ / 64, B_);
  transpose_kernel<<<tg, 256, 0, stream>>>(x, xt, xq);

  dim3 mg(N_ / NT, B_);
  mrconv_kernel<<<mg, 512, 0, stream>>>(xt, xq, eidx, Wb, bias, out);
}

// Round 15
// 92.779 us; speedup vs baseline: 1.4173x; 1.0237x over previous
//
#include <hip/hip_runtime.h>
#include <hip/hip_bf16.h>

#define B_ 4
#define C_IN_ 384
#define C_OUT_ 768
#define N_ 8192
#define K_ 16
#define FANIN_ 192     // 2*C_IN/GROUPS
#define NT 32          // n-columns per block; 8 waves x 4 cols
#define PADC (2*C_IN_ + 8)   // 776 shorts: merged row stride (split [x96|rel96] x4g)

typedef float f32x4 __attribute__((ext_vector_type(4)));
typedef short bf16x8 __attribute__((ext_vector_type(8)));
typedef short s16x2 __attribute__((ext_vector_type(2)));

__device__ __forceinline__ unsigned short f2b(float f) {
  union { float f; unsigned u; } v; v.f = f;
  unsigned r = v.u + 0x7FFFu + ((v.u >> 16) & 1u);  // RNE
  return (unsigned short)(r >> 16);
}

// ---- kernel 1: W fp32 -> bf16, k-reordered to [x96|rel96] per group ----
// merged k' in [0,192): k'<96 -> orig fanin 2k' (x), else 2(k'-96)+1 (rel)
__global__ __launch_bounds__(256) void wconv_kernel(const float* __restrict__ W,
                                                    unsigned short* __restrict__ Wb) {
  int i = blockIdx.x * 256 + threadIdx.x;
  if (i < C_OUT_ * FANIN_) {
    int kp = i % FANIN_;
    int o  = i / FANIN_;
    int f  = (kp < 96) ? (2 * kp) : (2 * (kp - 96) + 1);
    Wb[i] = f2b(W[(size_t)o * FANIN_ + f]);
  }
}

// ---- kernel 2: transpose x -> xt [B][N][C] bf16 + xq BIASED uint8 (x16+128) ----
__global__ __launch_bounds__(256) void transpose_kernel(const float* __restrict__ x,
                                                        unsigned short* __restrict__ xt,
                                                        unsigned char* __restrict__ xq) {
  __shared__ float tile[32][65];
  int n0 = blockIdx.x * 32;
  int c0 = blockIdx.y * 64;
  int b  = blockIdx.z;
  int tx = threadIdx.x & 31;
  int ty = threadIdx.x >> 5;
  const float* xp = x + (size_t)b * C_IN_ * N_;
  #pragma unroll
  for (int r = 0; r < 8; ++r) {
    int c = c0 + r * 8 + ty;
    tile[tx][r * 8 + ty] = xp[(size_t)c * N_ + n0 + tx];   // coalesced along n
  }
  __syncthreads();
  unsigned short* outp = xt + ((size_t)b * N_ + n0) * C_IN_ + c0;
  int cp = threadIdx.x & 31;
  int ny = threadIdx.x >> 5;
  #pragma unroll
  for (int p = 0; p < 4; ++p) {
    int nl = ny + p * 8;
    unsigned pk = (unsigned)f2b(tile[nl][cp * 2]) |
                  ((unsigned)f2b(tile[nl][cp * 2 + 1]) << 16);
    *(unsigned*)(outp + (size_t)nl * C_IN_ + cp * 2) = pk;
  }
  // biased uint8: q = clamp(rn(x*16)+128, 0, 255); diffs exact in 16-bit SWAR
  unsigned char* qout = xq + ((size_t)b * N_ + n0) * C_IN_ + c0;
  #pragma unroll
  for (int u = 0; u < 2; ++u) {
    int uu = u * 256 + threadIdx.x;
    int nl = uu >> 4;
    int c4 = uu & 15;
    unsigned pk = 0;
    #pragma unroll
    for (int e = 0; e < 4; ++e) {
      int q = __float2int_rn(tile[nl][c4 * 4 + e] * 16.0f) + 128;
      q = q < 0 ? 0 : (q > 255 ? 255 : q);
      pk |= ((unsigned)q) << (8 * e);
    }
    *(unsigned*)(qout + (size_t)nl * C_IN_ + c4 * 4) = pk;
  }
}

// ---- kernel 3: XCD-pinned batch slab; 2-rows-per-load gather + SWAR max -> MFMA ----
// ib&7 = XCD id: batch = xcd>>1, tile-half = xcd&1. Per-XCD gather working set =
// one batch's xq = 3.15 MB -> L2-resident (4 MB/XCD).
__global__ __launch_bounds__(512) void mrconv_kernel(
    const unsigned short* __restrict__ xt,   // [B][N][384] bf16 (self, exact)
    const unsigned char* __restrict__ xq,    // [B][N][384] biased uint8
    const int* __restrict__ eidx,            // [2][B][N][K]
    const unsigned short* __restrict__ Wb,   // [C_OUT][192] bf16, k-reordered
    const float* __restrict__ bias,          // [C_OUT]
    float* __restrict__ out)                 // [B][C_OUT][N]
{
  __shared__ unsigned short m_lds[NT][PADC];  // merged [x96|rel96] x 4 groups
  int ib   = blockIdx.x;
  int xcd  = ib & 7;
  int b    = xcd >> 1;                       // 2 XCDs per batch
  int thf  = xcd & 1;                        // tile half
  int tile = thf * 128 + (ib >> 3);          // 128 tiles per half
  int n0   = tile * NT;
  int tid  = threadIdx.x;
  int wv   = tid >> 6;         // 8 waves
  int lane = tid & 63;
  int h    = lane >> 5;        // k-parity handled by this lane (0=even,1=odd)
  int c    = lane & 31;        // 12-byte channel chunk within row

  const unsigned short* xtb = xt + (size_t)b * N_ * C_IN_;
  const unsigned char*  xqb = xq + (size_t)b * N_ * C_IN_;
  const int* e0p = eidx + ((size_t)b * N_) * K_;          // -> j
  const int* e1p = eidx + ((size_t)(B_ + b) * N_) * K_;   // -> i

  const unsigned char* xqc = xqb + c * 12;   // per-lane channel base

  for (int s = 0; s < 4; ++s) {
    int nl = wv * 4 + s;                     // 8 waves x 4 cols = 32
    int nb = __builtin_amdgcn_readfirstlane(n0 + nl);
    const int* e0 = e0p + (size_t)nb * K_;
    const int* e1 = e1p + (size_t)nb * K_;
    int sj[16], si[16];
    #pragma unroll
    for (int k = 0; k < 16; ++k) {
      sj[k] = __builtin_amdgcn_readfirstlane(e0[k]);
      si[k] = __builtin_amdgcn_readfirstlane(e1[k]);
    }
    uint4 xv;
    if (lane < 48) xv = *(const uint4*)(xtb + (size_t)nb * C_IN_ + lane * 8);

    s16x2 me[3], mo[3];                      // packed maxes: even/odd channels
    #pragma unroll
    for (int d = 0; d < 3; ++d) {
      me[d] = (s16x2){-512, -512};
      mo[d] = (s16x2){-512, -512};
    }

    #pragma unroll
    for (int t = 0; t < 8; ++t) {            // k = 2t + h: 2 rows per instruction
      int jrow = h ? sj[2 * t + 1] : sj[2 * t];   // v_cndmask from SGPRs
      int irow = h ? si[2 * t + 1] : si[2 * t];
      uint3 vj = *(const uint3*)(xqc + (size_t)jrow * C_IN_);   // 12 ch, dwordx3
      uint3 vi = *(const uint3*)(xqc + (size_t)irow * C_IN_);
      unsigned uj[3] = {vj.x, vj.y, vj.z};
      unsigned ui[3] = {vi.x, vi.y, vi.z};
      #pragma unroll
      for (int d = 0; d < 3; ++d) {
        // SWAR: biased bytes -> u16 lanes; diff exact; packed i16 max
        s16x2 je = __builtin_bit_cast(s16x2, uj[d] & 0x00FF00FFu);
        s16x2 jo = __builtin_bit_cast(s16x2, (uj[d] >> 8) & 0x00FF00FFu);
        s16x2 ie = __builtin_bit_cast(s16x2, ui[d] & 0x00FF00FFu);
        s16x2 io = __builtin_bit_cast(s16x2, (ui[d] >> 8) & 0x00FF00FFu);
        s16x2 de = je - ie;
        s16x2 dd = jo - io;
        me[d] = __builtin_elementwise_max(me[d], de);
        mo[d] = __builtin_elementwise_max(mo[d], dd);
      }
    }
    // merge k-parity halves (lane ^ 32 has same channels, other parity)
    #pragma unroll
    for (int d = 0; d < 3; ++d) {
      s16x2 oe = __builtin_bit_cast(s16x2, __shfl_xor(__builtin_bit_cast(int, me[d]), 32));
      me[d] = __builtin_elementwise_max(me[d], oe);
      s16x2 oo = __builtin_bit_cast(s16x2, __shfl_xor(__builtin_bit_cast(int, mo[d]), 32));
      mo[d] = __builtin_elementwise_max(mo[d], oo);
    }

    int col = nl;
    if (h == 0) {                            // lanes 0..31: rel channels [12c,12c+12)
      int gch = c * 12;                      // chunks align to group bounds (96/12=8)
      int g   = gch / 96;
      int pos = g * 192 + 96 + (gch - g * 96);
      unsigned short* dst = &m_lds[col][pos];
      unsigned w[6];
      #pragma unroll
      for (int d = 0; d < 3; ++d) {
        // ch 4d+0=me.x, 4d+1=mo.x, 4d+2=me.y, 4d+3=mo.y
        unsigned w0 = f2b((float)me[d][0] * 0.0625f);
        unsigned w1 = f2b((float)mo[d][0] * 0.0625f);
        unsigned w2 = f2b((float)me[d][1] * 0.0625f);
        unsigned w3 = f2b((float)mo[d][1] * 0.0625f);
        w[2 * d]     = w0 | (w1 << 16);
        w[2 * d + 1] = w2 | (w3 << 16);
      }
      *(uint2*)(dst)     = (uint2){w[0], w[1]};
      *(uint2*)(dst + 4) = (uint2){w[2], w[3]};
      *(uint2*)(dst + 8) = (uint2){w[4], w[5]};
    }
    if (lane < 48) {                         // x channels [8*lane, 8*lane+8)
      int gch = lane * 8;
      int g   = gch / 96;
      int pos = g * 192 + (gch - g * 96);
      *(uint4*)&m_lds[col][pos] = xv;
    }
  }
  __syncthreads();

  // -------- phase 2: grouped GEMM via MFMA (R7-verified shape) --------
  // wave wv -> group g = wv>>1, cout half = wv&1: owns 96 rows x 32 cols
  int g2   = wv >> 1;
  int half = wv & 1;
  int rb   = g2 * 192 + half * 96;   // cout base
  int l15  = lane & 15;
  int lhi  = lane >> 4;

  f32x4 acc[6][2];
  #pragma unroll
  for (int rt = 0; rt < 6; ++rt)
    #pragma unroll
    for (int ct = 0; ct < 2; ++ct)
      acc[rt][ct] = (f32x4){0.f, 0.f, 0.f, 0.f};

  #pragma unroll
  for (int ks = 0; ks < 6; ++ks) {           // K' = 192 = 6 x 32 (reordered k)
    int k0 = ks * 32 + lhi * 8;
    bf16x8 bfrag[2];
    #pragma unroll
    for (int ct = 0; ct < 2; ++ct) {
      int n = ct * 16 + l15;
      bfrag[ct] = *(const bf16x8*)&m_lds[n][g2 * 192 + k0];
    }
    #pragma unroll
    for (int rt = 0; rt < 6; ++rt) {
      int co = rb + rt * 16 + l15;
      bf16x8 afrag = *(const bf16x8*)(Wb + (size_t)co * FANIN_ + k0);
      #pragma unroll
      for (int ct = 0; ct < 2; ++ct)
        acc[rt][ct] = __builtin_amdgcn_mfma_f32_16x16x32_bf16(afrag, bfrag[ct],
                                                              acc[rt][ct], 0, 0, 0);
    }
  }

  // -------- epilogue: bias + ReLU, store --------
  float* outb = out + (size_t)b * C_OUT_ * N_;
  #pragma unroll
  for (int rt = 0; rt < 6; ++rt) {
    int co_b = rb + rt * 16 + lhi * 4;       // D row = (lane>>4)*4 + reg (m89-verified)
    #pragma unroll
    for (int ct = 0; ct < 2; ++ct) {
      int n = n0 + ct * 16 + l15;            // D col = lane&15
      #pragma unroll
      for (int r = 0; r < 4; ++r) {
        int co = co_b + r;
        float v = acc[rt][ct][r] + bias[co];
        outb[(size_t)co * N_ + n] = v > 0.f ? v : 0.f;
      }
    }
  }
}

extern "C" void kernel_launch(void* const* d_in, const int* in_sizes, int n_in,
                              void* d_out, int out_size, void* d_ws, size_t ws_size,
                              hipStream_t stream) {
  const float* x    = (const float*)d_in[0];
  const int*   eidx = (const int*)d_in[1];
  const float* W    = (const float*)d_in[2];
  const float* bias = (const float*)d_in[3];
  float* out = (float*)d_out;

  unsigned short* xt = (unsigned short*)d_ws;                 // 25.2 MB bf16
  unsigned short* Wb = xt + (size_t)B_ * N_ * C_IN_;          // 0.3 MB bf16
  unsigned char*  xq = (unsigned char*)(Wb + (size_t)C_OUT_ * FANIN_); // 12.6 MB u8

  wconv_kernel<<<(C_OUT_ * FANIN_ + 255) / 256, 256, 0, stream>>>(W, Wb);

  dim3 tg(N_ / 32, C_IN_ / 64, B_);
  transpose_kernel<<<tg, 256, 0, stream>>>(x, xt, xq);

  int nblk = B_ * (N_ / NT);   // 1024; ib&7 = XCD -> (batch, tile-half)
  mrconv_kernel<<<nblk, 512, 0, stream>>>(xt, xq, eidx, Wb, bias, out);
}